// Round 5
// baseline (719.075 us; speedup 1.0000x reference)
//
#include <hip/hip_runtime.h>
#include <hip/hip_bf16.h>

typedef unsigned short u16;
typedef unsigned int u32;
typedef unsigned long long u64;
typedef float f32x4 __attribute__((ext_vector_type(4)));
typedef u16 u16x4 __attribute__((ext_vector_type(4)));
typedef u16 u16x8 __attribute__((ext_vector_type(8)));

// ---------- helpers ----------
__device__ __forceinline__ u16 f2b(float f) {
  return __builtin_bit_cast(u16, __float2bfloat16(f));
}
__device__ __forceinline__ float b2f(u16 u) {
  return __builtin_bit_cast(float, ((u32)u) << 16);
}
__device__ __forceinline__ f32x4 ldb4(const u16* __restrict__ p) {
  u16x4 v = *(const u16x4*)p;
  f32x4 r;
#pragma unroll
  for (int i = 0; i < 4; ++i) r[i] = b2f(v[i]);
  return r;
}
__device__ __forceinline__ f32x4 sigm4(f32x4 x) {
  f32x4 r;
#pragma unroll
  for (int i = 0; i < 4; ++i) r[i] = 1.0f / (1.0f + __expf(-x[i]));
  return r;
}
__device__ __forceinline__ f32x4 tanh4(f32x4 x) {
  f32x4 r;
#pragma unroll
  for (int i = 0; i < 4; ++i) {
    float xx = fminf(fmaxf(x[i], -15.0f), 15.0f);
    float e = __expf(2.0f * xx);
    r[i] = (e - 1.0f) / (e + 1.0f);
  }
  return r;
}

__device__ __forceinline__ void gload_lds16(const void* g, void* l) {
  typedef __attribute__((address_space(1))) const u32 gq_t;
  typedef __attribute__((address_space(3))) u32 lq_t;
  gq_t* gp = (gq_t*)(u64)(size_t)g;
  lq_t* lp = (lq_t*)(u32)(size_t)l;
  __builtin_amdgcn_global_load_lds(gp, lp, 16, 0, 0);
}

// asm MFMA: register dataflow links it to the asm ds_read outputs; ordering
// vs counted lgkm waits is pinned by one sched_barrier(0) per phase.
__device__ __forceinline__ f32x4 mfma_bf16(u16x8 a, u16x8 b, f32x4 c) {
  asm("v_mfma_f32_16x16x32_bf16 %0, %1, %2, %0" : "+v"(c) : "v"(a), "v"(b));
  return c;
}

// ---------- kernel 1: cast x, h0 to bf16 ----------
__global__ __launch_bounds__(256) void cvt2_kernel(
    const f32x4* __restrict__ x, const f32x4* __restrict__ h,
    u16x4* __restrict__ xb, u16x4* __restrict__ hb, int n4) {
  for (int i = blockIdx.x * blockDim.x + threadIdx.x; i < n4;
       i += gridDim.x * blockDim.x) {
    f32x4 a = x[i], b = h[i];
    u16x4 ra, rb;
#pragma unroll
    for (int j = 0; j < 4; ++j) { ra[j] = f2b(a[j]); rb[j] = f2b(b[j]); }
    xb[i] = ra;
    hb[i] = rb;
  }
}

// ---------- kernel 2: pack + transpose weights to bf16 [N][K] ----------
__global__ __launch_bounds__(256) void packw_kernel(
    const float* __restrict__ W_ioux, const float* __restrict__ b_ioux,
    const float* __restrict__ W_iouh_r, const float* __restrict__ W_iouh_l,
    const float* __restrict__ W_fx, const float* __restrict__ b_fx,
    const float* __restrict__ W_fh0, const float* __restrict__ W_fh1,
    const float* __restrict__ W_fh2, const float* __restrict__ W_fh3,
    u16* __restrict__ WxT, u16* __restrict__ WhT, float* __restrict__ bcat) {
  const int t = blockIdx.x * 256 + threadIdx.x;
  const int NXW = 4096 * 128;
  float v[8];
  if (t < NXW) {
    const int n = t & 4095;
    const int k0 = (t >> 12) * 8;
    if (n < 3072) {
#pragma unroll
      for (int j = 0; j < 8; ++j) v[j] = W_ioux[(size_t)(k0 + j) * 3072 + n];
    } else {
#pragma unroll
      for (int j = 0; j < 8; ++j) v[j] = W_fx[(size_t)(k0 + j) * 1024 + (n - 3072)];
    }
    u16x8 o;
#pragma unroll
    for (int j = 0; j < 8; ++j) o[j] = f2b(v[j]);
    *(u16x8*)(WxT + (size_t)n * 1024 + k0) = o;
    if (k0 == 0) bcat[n] = (n < 3072) ? b_ioux[n] : b_fx[n - 3072];
  } else {
    const int u = t - NXW;
    const int m = u & 8191;
    const int k0 = (u >> 13) * 8;
    if (m < 3072) {
#pragma unroll
      for (int j = 0; j < 8; ++j) v[j] = W_iouh_r[(size_t)(k0 + j) * 3072 + m];
    } else if (m < 6144) {
#pragma unroll
      for (int j = 0; j < 8; ++j) v[j] = W_iouh_l[(size_t)(k0 + j) * 3072 + (m - 3072)];
    } else if (m < 7168) {
      const int c = m - 6144;
#pragma unroll
      for (int j = 0; j < 8; ++j)
        v[j] = W_fh0[(size_t)(k0 + j) * 1024 + c] + W_fh1[(size_t)(k0 + j) * 1024 + c];
    } else {
      const int c = m - 7168;
#pragma unroll
      for (int j = 0; j < 8; ++j)
        v[j] = W_fh2[(size_t)(k0 + j) * 1024 + c] + W_fh3[(size_t)(k0 + j) * 1024 + c];
    }
    u16x8 o;
#pragma unroll
    for (int j = 0; j < 8; ++j) o[j] = f2b(v[j]);
    *(u16x8*)(WhT + (size_t)m * 1024 + k0) = o;
  }
}

// ---------- kernel 3: 256x256 NT GEMM, frag-double-buffered pipeline --------
// 512 threads = 8 waves (2M x 4N), wave tile 128x64. LDS 128KB, XOR-swizzled.
// ds_reads are issued one phase BEFORE their consuming MFMA; counted lgkm
// waits certify only the older reads -> LDS pipe drains under MFMA (T3/T4).
// Region/staging schedule identical to the round-2/4 proven layout.

template <int MS, int NS>
__device__ __forceinline__ void mfma_q(u16x8 (&ar)[4][2], u16x8 (&br)[2][2],
                                       f32x4 (&acc)[2][4][2][2]) {
#pragma unroll
  for (int kk = 0; kk < 2; ++kk)
#pragma unroll
    for (int fm = 0; fm < 4; ++fm)
#pragma unroll
      for (int fn = 0; fn < 2; ++fn)
        acc[MS][fm][NS][fn] =
            mfma_bf16(ar[fm][kk], br[fn][kk], acc[MS][fm][NS][fn]);
}

#define DSR(d, va, imm) \
  asm volatile("ds_read_b128 %0, %1 offset:%2" : "=v"(d) : "v"(va), "n"(imm))

#define LDA8(P, MS, AR)                                   \
  DSR(AR[0][0], a_k0, (P)*32768 + (MS)*16384 + 0);        \
  DSR(AR[0][1], a_k1, (P)*32768 + (MS)*16384 + 0);        \
  DSR(AR[1][0], a_k0, (P)*32768 + (MS)*16384 + 2048);     \
  DSR(AR[1][1], a_k1, (P)*32768 + (MS)*16384 + 2048);     \
  DSR(AR[2][0], a_k0, (P)*32768 + (MS)*16384 + 4096);     \
  DSR(AR[2][1], a_k1, (P)*32768 + (MS)*16384 + 4096);     \
  DSR(AR[3][0], a_k0, (P)*32768 + (MS)*16384 + 6144);     \
  DSR(AR[3][1], a_k1, (P)*32768 + (MS)*16384 + 6144)

#define LDB4(P, NS, BR)                                   \
  DSR(BR[0][0], b_k0, (P)*32768 + (NS)*16384 + 0);        \
  DSR(BR[0][1], b_k1, (P)*32768 + (NS)*16384 + 0);        \
  DSR(BR[1][0], b_k0, (P)*32768 + (NS)*16384 + 2048);     \
  DSR(BR[1][1], b_k1, (P)*32768 + (NS)*16384 + 2048)

#define BARRIER __builtin_amdgcn_s_barrier()
#define WAITL(n)                                                \
  do {                                                          \
    asm volatile("s_waitcnt lgkmcnt(" #n ")" ::: "memory");     \
    __builtin_amdgcn_sched_barrier(0);                          \
  } while (0)
#define VMCNT(n) asm volatile("s_waitcnt vmcnt(" #n ")" ::: "memory")

__global__ __launch_bounds__(512, 2) void gemm_bt(
    const u16* __restrict__ A, const u16* __restrict__ Bt,
    u16* __restrict__ C, const float* __restrict__ bias, int N, int nk) {
  __shared__ u16 lds_u16[65536];  // 128 KB: A 2x32KB @0, B 2x32KB @65536
  char* ldsb = (char*)lds_u16;
  const int tid = threadIdx.x;
  const int lane = tid & 63;
  const int wave = tid >> 6;
  const int wm = wave >> 2, wn = wave & 3;
  const int K = nk * 64;

  // XCD-aware block swizzle (nwg % 8 == 0 by construction)
  const int nbn = N >> 8;
  const int nwg = gridDim.x;
  const int bid = blockIdx.x;
  const int swz = (bid & 7) * (nwg >> 3) + (bid >> 3);
  const int bm = swz / nbn, bn = swz % nbn;

  // staging source: inverse-XOR-swizzled so swizzled ds_reads see linear data
  const int srow = tid >> 3;
  const int ssw = (((tid & 7) * 16) ^ ((srow & 7) << 4)) >> 1;
  const u16* Ab = A + (size_t)(bm * 256 + srow) * K + ssw;
  const u16* Bb = Bt + (size_t)(bn * 256 + srow) * K + ssw;

#define SAg(P, c, kt)                                           \
  gload_lds16(Ab + (size_t)(c) * 64 * K + (size_t)(kt) * 64,    \
              ldsb + (P) * 32768 + (c) * 8192 + tid * 16)
#define SBg(P, c, kt)                                                  \
  gload_lds16(Bb + (size_t)(c) * 64 * K + (size_t)(kt) * 64,           \
              ldsb + 65536 + (P) * 32768 + (c) * 8192 + tid * 16)

  // fragment read base addresses (byte): XOR swizzle depends only on lane
  const int lb15 = lane & 15;
  const int lh16 = (lane >> 4) * 16;
  const int sw = (lane & 7) << 4;
  const u32 lbase = (u32)(size_t)ldsb;
  const u32 a_k0 = lbase + (u32)((wm * 64 + lb15) * 128 + (lh16 ^ sw));
  const u32 a_k1 = lbase + (u32)((wm * 64 + lb15) * 128 + ((64 + lh16) ^ sw));
  const u32 b_k0 = lbase + 65536u + (u32)((wn * 32 + lb15) * 128 + (lh16 ^ sw));
  const u32 b_k1 =
      lbase + 65536u + (u32)((wn * 32 + lb15) * 128 + ((64 + lh16) ^ sw));

  u16x8 arA[4][2], arB[4][2], brA[2][2], brB[2][2];
  f32x4 acc[2][4][2][2] = {};

  // prologue: tile0 all 8 chunks -> buf0; tile1's A01,B23 -> buf1
  {
    const int s1 = (nk > 1) ? 1 : 0;
    SAg(0, 0, 0); SAg(0, 1, 0); SAg(0, 2, 0); SAg(0, 3, 0);
    SBg(0, 0, 0); SBg(0, 1, 0); SBg(0, 2, 0); SBg(0, 3, 0);
    SAg(1, 0, s1); SAg(1, 1, s1);
    SBg(1, 2, s1); SBg(1, 3, s1);
  }
  VMCNT(4);  // tile0 landed; tile1's 4 stay in flight
  BARRIER;

#define TILEBODY(P, Tcur)                                               \
  {                                                                     \
    const int s1 = ((Tcur) + 1 < nk) ? (Tcur) + 1 : nk - 1;             \
    const int s2 = ((Tcur) + 2 < nk) ? (Tcur) + 2 : nk - 1;             \
    /* entry: issue Q0 frags (12 reads) */                              \
    LDB4(P, 0, brA);                                                    \
    LDA8(P, 0, arA);                                                    \
    /* P1: issue brB(4); stage q-A23(T+1); wait entry; MFMA Q0 */       \
    LDB4(P, 1, brB);                                                    \
    SAg((P) ^ 1, 2, s1); SAg((P) ^ 1, 3, s1);                           \
    WAITL(4);                                                           \
    __builtin_amdgcn_s_setprio(1);                                      \
    mfma_q<0, 0>(arA, brA, acc);                                        \
    __builtin_amdgcn_s_setprio(0);                                      \
    BARRIER;                                                            \
    /* P2: issue arB(8); stage q-B01(T+1); wait brB; MFMA Q1 */         \
    LDA8(P, 1, arB);                                                    \
    SBg((P) ^ 1, 0, s1); SBg((P) ^ 1, 1, s1);                           \
    WAITL(8);                                                           \
    __builtin_amdgcn_s_setprio(1);                                      \
    mfma_q<0, 1>(arA, brB, acc);                                        \
    __builtin_amdgcn_s_setprio(0);                                      \
    BARRIER;                                                            \
    /* P3: stage p-A01(T+2); wait arB; MFMA Q2 */                       \
    SAg(P, 0, s2); SAg(P, 1, s2);                                       \
    WAITL(0);                                                           \
    __builtin_amdgcn_s_setprio(1);                                      \
    mfma_q<1, 1>(arB, brB, acc);                                        \
    __builtin_amdgcn_s_setprio(0);                                      \
    BARRIER;                                                            \
    /* P4: stage p-B23(T+2); MFMA Q3 (regs resident); counted vmcnt */  \
    SBg(P, 2, s2); SBg(P, 3, s2);                                       \
    __builtin_amdgcn_s_setprio(1);                                      \
    mfma_q<1, 0>(arB, brA, acc);                                        \
    __builtin_amdgcn_s_setprio(0);                                      \
    VMCNT(4);                                                           \
    BARRIER;                                                            \
  }

  for (int T = 0; T < nk; T += 2) {
    TILEBODY(0, T);
    TILEBODY(1, T + 1);
  }
  VMCNT(0);

  // epilogue: wave rows {wm*64.., 128+wm*64..}, cols {wn*32.., 128+wn*32..}
#pragma unroll
  for (int ms = 0; ms < 2; ++ms)
#pragma unroll
    for (int fm = 0; fm < 4; ++fm) {
      const int row0 = bm * 256 + ms * 128 + wm * 64 + fm * 16 + ((lane >> 4) * 4);
#pragma unroll
      for (int ns = 0; ns < 2; ++ns)
#pragma unroll
        for (int fn = 0; fn < 2; ++fn) {
          const int col = bn * 256 + ns * 128 + wn * 32 + fn * 16 + lb15;
          const float bv = bias ? bias[col] : 0.0f;
#pragma unroll
          for (int r = 0; r < 4; ++r)
            C[(size_t)(row0 + r) * N + col] = f2b(acc[ms][fm][ns][fn][r] + bv);
        }
    }
#undef SAg
#undef SBg
#undef TILEBODY
}

// ---------- kernel 4: fused scatter/gather + gates ----------
__global__ __launch_bounds__(256) void fused_epi(
    const u16* __restrict__ XO, const u16* __restrict__ HO,
    const float* __restrict__ h0, const float* __restrict__ c0,
    const int* __restrict__ idd, const int* __restrict__ idr,
    const int* __restrict__ idl, float* __restrict__ outh,
    float* __restrict__ outc, int b0) {
  __shared__ int listD[512], listR[512], listL[512];
  __shared__ int cnt[3];
  const int j = blockIdx.x;
  const int lb = blockIdx.y;
  const int b = b0 + lb;
  const int tid = threadIdx.x;
  const int lane = tid & 63;
  const int wave = tid >> 6;

  if (wave < 3) {
    const int* ids = (wave == 0 ? idd : (wave == 1 ? idr : idl)) + (size_t)b * 512;
    int* lst = (wave == 0 ? listD : (wave == 1 ? listR : listL));
    int base = 0;
#pragma unroll
    for (int c2 = 0; c2 < 8; ++c2) {
      int l = c2 * 64 + lane;
      int id = ids[l];
      u64 m = __ballot(id == j);
      if (id == j) {
        int pos = __popcll(m & ((1ull << lane) - 1ull));
        lst[base + pos] = l;
      }
      base += __popcll(m);
    }
    if (lane == 0) cnt[wave] = base;
  }
  __syncthreads();

  const int nD = cnt[0], nR = cnt[1], nL = cnt[2];
  const size_t grow = (size_t)b * 512 + j;
  const int k = tid * 4;

  if (!((nD > 0) && (j != 0))) {
    f32x4 hv = *(const f32x4*)(h0 + grow * 1024 + k);
    f32x4 cv = *(const f32x4*)(c0 + grow * 1024 + k);
    *(f32x4*)(outh + grow * 1024 + k) = hv;
    *(f32x4*)(outc + grow * 1024 + k) = cv;
    return;
  }

  const size_t lrow = (size_t)lb * 512 + j;
  const u16* xo = XO + lrow * 4096;
  f32x4 ai = ldb4(xo + k);
  f32x4 ao = ldb4(xo + 1024 + k);
  f32x4 au = ldb4(xo + 2048 + k);
  f32x4 fx = ldb4(xo + 3072 + k);

  for (int t = 0; t < nR; ++t) {
    const u16* hr = HO + ((size_t)lb * 512 + listR[t]) * 8192;
    ai += ldb4(hr + k);
    ao += ldb4(hr + 1024 + k);
    au += ldb4(hr + 2048 + k);
  }
  for (int t = 0; t < nL; ++t) {
    const u16* hl = HO + ((size_t)lb * 512 + listL[t]) * 8192;
    ai += ldb4(hl + 3072 + k);
    ao += ldb4(hl + 4096 + k);
    au += ldb4(hl + 5120 + k);
  }
  f32x4 gi = sigm4(ai), go = sigm4(ao), gu = tanh4(au);
  f32x4 c = gi * gu;
  for (int t = 0; t < nD; ++t) {
    int child = listD[t];
    int rr = idr[(size_t)b * 512 + child];
    int ll = idl[(size_t)b * 512 + child];
    f32x4 fpre = fx + ldb4(HO + ((size_t)lb * 512 + rr) * 8192 + 6144 + k) +
                 ldb4(HO + ((size_t)lb * 512 + ll) * 8192 + 7168 + k);
    f32x4 fg = sigm4(fpre);
    f32x4 cc = *(const f32x4*)(c0 + ((size_t)b * 512 + child) * 1024 + k);
    c += fg * cc;
  }
  f32x4 h = go * tanh4(c);
  *(f32x4*)(outh + grow * 1024 + k) = h;
  *(f32x4*)(outc + grow * 1024 + k) = c;
}

// ---------- host ----------
extern "C" void kernel_launch(void* const* d_in, const int* in_sizes, int n_in,
                              void* d_out, int out_size, void* d_ws,
                              size_t ws_size, hipStream_t stream) {
  const float* x = (const float*)d_in[0];
  const float* h0 = (const float*)d_in[1];
  const float* c0 = (const float*)d_in[2];
  const float* W_ioux = (const float*)d_in[3];
  const float* b_ioux = (const float*)d_in[4];
  const float* W_iouh_r = (const float*)d_in[5];
  const float* W_iouh_l = (const float*)d_in[6];
  const float* W_fx = (const float*)d_in[7];
  const float* b_fx = (const float*)d_in[8];
  const float* W_fh0 = (const float*)d_in[9];
  const float* W_fh1 = (const float*)d_in[10];
  const float* W_fh2 = (const float*)d_in[11];
  const float* W_fh3 = (const float*)d_in[12];
  const int* idd = (const int*)d_in[13];
  const int* idr = (const int*)d_in[14];
  const int* idl = (const int*)d_in[15];

  const size_t M = 16384;  // B*L
  char* p = (char*)d_ws;
  u16* Xb = (u16*)p;   p += M * 1024 * 2;
  u16* Hb = (u16*)p;   p += M * 1024 * 2;
  u16* WxT = (u16*)p;  p += (size_t)4096 * 1024 * 2;
  u16* WhT = (u16*)p;  p += (size_t)8192 * 1024 * 2;
  float* bcat = (float*)p; p += (size_t)4096 * 4;
  const size_t base_sz = (size_t)(p - (char*)d_ws);
  const size_t per_cb = (size_t)512 * 4096 * 2 + (size_t)512 * 8192 * 2;
  int CB = 32;
  while (CB > 1 && base_sz + (size_t)CB * per_cb > ws_size) CB >>= 1;
  u16* XO = (u16*)p;   p += (size_t)CB * 512 * 4096 * 2;
  u16* HO = (u16*)p;

  float* outh = (float*)d_out;
  float* outc = outh + M * 1024;

  cvt2_kernel<<<2048, 256, 0, stream>>>((const f32x4*)x, (const f32x4*)h0,
                                        (u16x4*)Xb, (u16x4*)Hb,
                                        (int)(M * 1024 / 4));
  packw_kernel<<<6144, 256, 0, stream>>>(W_ioux, b_ioux, W_iouh_r, W_iouh_l,
                                         W_fx, b_fx, W_fh0, W_fh1, W_fh2, W_fh3,
                                         WxT, WhT, bcat);

  const int nc = 32 / CB;
  for (int c = 0; c < nc; ++c) {
    const int mrows = CB * 512;
    const u16* Ax = Xb + (size_t)c * CB * 512 * 1024;
    const u16* Ah = Hb + (size_t)c * CB * 512 * 1024;
    gemm_bt<<<(mrows / 256) * (4096 / 256), 512, 0, stream>>>(Ax, WxT, XO, bcat,
                                                              4096, 1024 / 64);
    gemm_bt<<<(mrows / 256) * (8192 / 256), 512, 0, stream>>>(Ah, WhT, HO,
                                                              nullptr, 8192,
                                                              1024 / 64);
    fused_epi<<<dim3(512, CB), 256, 0, stream>>>(XO, HO, h0, c0, idd, idr, idl,
                                                 outh, outc, c * CB);
  }
}

// Round 6
// 581.049 us; speedup vs baseline: 1.2375x; 1.2375x over previous
//
#include <hip/hip_runtime.h>
#include <hip/hip_bf16.h>

typedef unsigned short u16;
typedef unsigned int u32;
typedef unsigned long long u64;
typedef float f32x4 __attribute__((ext_vector_type(4)));
typedef u16 u16x4 __attribute__((ext_vector_type(4)));
typedef u16 u16x8 __attribute__((ext_vector_type(8)));
typedef short s16x8 __attribute__((ext_vector_type(8)));

// ---------- helpers ----------
__device__ __forceinline__ u16 f2b(float f) {
  return __builtin_bit_cast(u16, __float2bfloat16(f));
}
__device__ __forceinline__ float b2f(u16 u) {
  return __builtin_bit_cast(float, ((u32)u) << 16);
}
__device__ __forceinline__ f32x4 ldb4(const u16* __restrict__ p) {
  u16x4 v = *(const u16x4*)p;
  f32x4 r;
#pragma unroll
  for (int i = 0; i < 4; ++i) r[i] = b2f(v[i]);
  return r;
}
__device__ __forceinline__ f32x4 sigm4(f32x4 x) {
  f32x4 r;
#pragma unroll
  for (int i = 0; i < 4; ++i) r[i] = 1.0f / (1.0f + __expf(-x[i]));
  return r;
}
__device__ __forceinline__ f32x4 tanh4(f32x4 x) {
  f32x4 r;
#pragma unroll
  for (int i = 0; i < 4; ++i) {
    float xx = fminf(fmaxf(x[i], -15.0f), 15.0f);
    float e = __expf(2.0f * xx);
    r[i] = (e - 1.0f) / (e + 1.0f);
  }
  return r;
}

__device__ __forceinline__ void gload_lds16(const void* g, void* l) {
  typedef __attribute__((address_space(1))) const u32 gq_t;
  typedef __attribute__((address_space(3))) u32 lq_t;
  gq_t* gp = (gq_t*)(u64)(size_t)g;
  lq_t* lp = (lq_t*)(u32)(size_t)l;
  __builtin_amdgcn_global_load_lds(gp, lp, 16, 0, 0);
}

// Builtin MFMA: compiler sees operand deps -> inserts its own counted lgkm
// waits and pipelines ds_reads under the MFMA stream (m97 disasm evidence).
__device__ __forceinline__ f32x4 mfma_b(u16x8 a, u16x8 b, f32x4 c) {
  return __builtin_amdgcn_mfma_f32_16x16x32_bf16(
      __builtin_bit_cast(s16x8, a), __builtin_bit_cast(s16x8, b), c, 0, 0, 0);
}

// ---------- kernel 1: cast x, h0 to bf16 ----------
__global__ __launch_bounds__(256) void cvt2_kernel(
    const f32x4* __restrict__ x, const f32x4* __restrict__ h,
    u16x4* __restrict__ xb, u16x4* __restrict__ hb, int n4) {
  for (int i = blockIdx.x * blockDim.x + threadIdx.x; i < n4;
       i += gridDim.x * blockDim.x) {
    f32x4 a = x[i], b = h[i];
    u16x4 ra, rb;
#pragma unroll
    for (int j = 0; j < 4; ++j) { ra[j] = f2b(a[j]); rb[j] = f2b(b[j]); }
    xb[i] = ra;
    hb[i] = rb;
  }
}

// ---------- kernel 2: pack + transpose weights to bf16 [N][K] ----------
__global__ __launch_bounds__(256) void packw_kernel(
    const float* __restrict__ W_ioux, const float* __restrict__ b_ioux,
    const float* __restrict__ W_iouh_r, const float* __restrict__ W_iouh_l,
    const float* __restrict__ W_fx, const float* __restrict__ b_fx,
    const float* __restrict__ W_fh0, const float* __restrict__ W_fh1,
    const float* __restrict__ W_fh2, const float* __restrict__ W_fh3,
    u16* __restrict__ WxT, u16* __restrict__ WhT, float* __restrict__ bcat) {
  const int t = blockIdx.x * 256 + threadIdx.x;
  const int NXW = 4096 * 128;
  float v[8];
  if (t < NXW) {
    const int n = t & 4095;
    const int k0 = (t >> 12) * 8;
    if (n < 3072) {
#pragma unroll
      for (int j = 0; j < 8; ++j) v[j] = W_ioux[(size_t)(k0 + j) * 3072 + n];
    } else {
#pragma unroll
      for (int j = 0; j < 8; ++j) v[j] = W_fx[(size_t)(k0 + j) * 1024 + (n - 3072)];
    }
    u16x8 o;
#pragma unroll
    for (int j = 0; j < 8; ++j) o[j] = f2b(v[j]);
    *(u16x8*)(WxT + (size_t)n * 1024 + k0) = o;
    if (k0 == 0) bcat[n] = (n < 3072) ? b_ioux[n] : b_fx[n - 3072];
  } else {
    const int u = t - NXW;
    const int m = u & 8191;
    const int k0 = (u >> 13) * 8;
    if (m < 3072) {
#pragma unroll
      for (int j = 0; j < 8; ++j) v[j] = W_iouh_r[(size_t)(k0 + j) * 3072 + m];
    } else if (m < 6144) {
#pragma unroll
      for (int j = 0; j < 8; ++j) v[j] = W_iouh_l[(size_t)(k0 + j) * 3072 + (m - 3072)];
    } else if (m < 7168) {
      const int c = m - 6144;
#pragma unroll
      for (int j = 0; j < 8; ++j)
        v[j] = W_fh0[(size_t)(k0 + j) * 1024 + c] + W_fh1[(size_t)(k0 + j) * 1024 + c];
    } else {
      const int c = m - 7168;
#pragma unroll
      for (int j = 0; j < 8; ++j)
        v[j] = W_fh2[(size_t)(k0 + j) * 1024 + c] + W_fh3[(size_t)(k0 + j) * 1024 + c];
    }
    u16x8 o;
#pragma unroll
    for (int j = 0; j < 8; ++j) o[j] = f2b(v[j]);
    *(u16x8*)(WhT + (size_t)m * 1024 + k0) = o;
  }
}

// ---------- kernel 3: 256x256 4-phase NT GEMM (m201 asm discipline) --------
// 512 threads = 8 waves (2M x 4N), wave tile 128x64. LDS 128KB XOR-swizzled.
// Per phase: {plain-C++ ds_read frags, stage 2 gload_lds, s_barrier,
// plain "s_waitcnt lgkmcnt(0)" (no clobber), setprio, 16 MFMA, setprio,
// s_barrier}. ONE counted vmcnt(4) per K-tile. NO memory-clobber fences, NO
// sched_barriers: every extra volatile-asm/clobber is a scheduler region
// break that pins loads into their phase (R3/R4/R5 evidence, m141).

#define BARRIER __builtin_amdgcn_s_barrier()
#define LGKM0 asm volatile("s_waitcnt lgkmcnt(0)")
#define VMCNT(n) asm volatile("s_waitcnt vmcnt(" #n ")")

__global__ __launch_bounds__(512, 2) void gemm_bt(
    const u16* __restrict__ A, const u16* __restrict__ Bt,
    u16* __restrict__ C, const float* __restrict__ bias, int N, int nk) {
  __shared__ u16 lds_u16[65536];  // 128 KB: A 2x32KB @0, B 2x32KB @65536
  char* ldsb = (char*)lds_u16;
  const int tid = threadIdx.x;
  const int lane = tid & 63;
  const int wave = tid >> 6;
  const int wm = wave >> 2, wn = wave & 3;
  const int K = nk * 64;

  // XCD-aware block swizzle (nwg % 8 == 0 by construction)
  const int nbn = N >> 8;
  const int nwg = gridDim.x;
  const int bid = blockIdx.x;
  const int swz = (bid & 7) * (nwg >> 3) + (bid >> 3);
  const int bm = swz / nbn, bn = swz % nbn;

  // staging source: inverse-XOR-swizzled so swizzled ds_reads see linear data
  const int srow = tid >> 3;
  const int ssw = (((tid & 7) * 16) ^ ((srow & 7) << 4)) >> 1;
  const u16* Ab = A + (size_t)(bm * 256 + srow) * K + ssw;
  const u16* Bb = Bt + (size_t)(bn * 256 + srow) * K + ssw;

#define SAg(PB, c, kt)                                          \
  gload_lds16(Ab + (size_t)(c) * 64 * K + (size_t)(kt) * 64,    \
              ldsb + (PB) + (c) * 8192 + tid * 16)
#define SBg(PB, c, kt)                                          \
  gload_lds16(Bb + (size_t)(c) * 64 * K + (size_t)(kt) * 64,    \
              ldsb + 65536 + (PB) + (c) * 8192 + tid * 16)

  // fragment read offsets (XOR swizzle depends only on lane)
  const int lb15 = lane & 15;
  const int lh16 = (lane >> 4) * 16;
  const int sw = (lane & 7) << 4;
  int a_off[2], b_off[2];
  a_off[0] = (wm * 64 + lb15) * 128 + (lh16 ^ sw);
  a_off[1] = (wm * 64 + lb15) * 128 + ((64 + lh16) ^ sw);
  b_off[0] = 65536 + (wn * 32 + lb15) * 128 + (lh16 ^ sw);
  b_off[1] = 65536 + (wn * 32 + lb15) * 128 + ((64 + lh16) ^ sw);

#define LDA(AR, PB, MS)                                                    \
  _Pragma("unroll") for (int fm = 0; fm < 4; ++fm) _Pragma("unroll")       \
      for (int kk = 0; kk < 2; ++kk) AR[fm][kk] =                          \
          *(const u16x8*)(ldsb + (PB) + a_off[kk] + (MS)*16384 + fm * 2048)
#define LDB(BR, PB, NS)                                                    \
  _Pragma("unroll") for (int fn = 0; fn < 2; ++fn) _Pragma("unroll")       \
      for (int kk = 0; kk < 2; ++kk) BR[fn][kk] =                          \
          *(const u16x8*)(ldsb + (PB) + b_off[kk] + (NS)*16384 + fn * 2048)
#define MFMAQ(MS, NS, AR, BR)                                              \
  _Pragma("unroll") for (int kk = 0; kk < 2; ++kk) _Pragma("unroll")       \
      for (int fm = 0; fm < 4; ++fm) _Pragma("unroll")                     \
      for (int fn = 0; fn < 2; ++fn) acc[MS][fm][NS][fn] =                 \
          mfma_b(AR[fm][kk], BR[fn][kk], acc[MS][fm][NS][fn])

  u16x8 ar0[4][2], ar1[4][2], br0[2][2], br1[2][2];
  f32x4 acc[2][4][2][2] = {};

  // prologue: tile0 all 8 chunks -> buf0; tile1's A01,B23 -> buf1
  {
    const int s1 = (nk > 1) ? 1 : 0;
    SAg(0, 0, 0); SAg(0, 1, 0); SAg(0, 2, 0); SAg(0, 3, 0);
    SBg(0, 0, 0); SBg(0, 1, 0); SBg(0, 2, 0); SBg(0, 3, 0);
    SAg(32768, 0, s1); SAg(32768, 1, s1);
    SBg(32768, 2, s1); SBg(32768, 3, s1);
  }
  VMCNT(4);  // tile0 landed; tile1's 4 stay in flight
  BARRIER;

  // TILEBODY with literal buffer byte-offset PB (0 or 32768): all LDS
  // addresses fold to register+immediate. QB = other buffer.
#define TILEBODY(PB, QB, Tcur)                                          \
  {                                                                     \
    const int s1 = ((Tcur) + 1 < nk) ? (Tcur) + 1 : nk - 1;             \
    const int s2 = ((Tcur) + 2 < nk) ? (Tcur) + 2 : nk - 1;             \
    /* P1 (m0,n0): read br0,ar0 from PB; stage QB A23 (tile T+1) */     \
    LDB(br0, PB, 0);                                                    \
    LDA(ar0, PB, 0);                                                    \
    SAg(QB, 2, s1); SAg(QB, 3, s1);                                     \
    BARRIER;                                                            \
    LGKM0;                                                              \
    __builtin_amdgcn_s_setprio(1);                                      \
    MFMAQ(0, 0, ar0, br0);                                              \
    __builtin_amdgcn_s_setprio(0);                                      \
    BARRIER;                                                            \
    /* P2 (m0,n1): read br1; stage QB B01 (tile T+1) */                 \
    LDB(br1, PB, 1);                                                    \
    SBg(QB, 0, s1); SBg(QB, 1, s1);                                     \
    BARRIER;                                                            \
    LGKM0;                                                              \
    __builtin_amdgcn_s_setprio(1);                                      \
    MFMAQ(0, 1, ar0, br1);                                              \
    __builtin_amdgcn_s_setprio(0);                                      \
    BARRIER;                                                            \
    /* P3 (m1,n1): read ar1; stage PB A01 (tile T+2) */                 \
    LDA(ar1, PB, 1);                                                    \
    SAg(PB, 0, s2); SAg(PB, 1, s2);                                     \
    BARRIER;                                                            \
    LGKM0;                                                              \
    __builtin_amdgcn_s_setprio(1);                                      \
    MFMAQ(1, 1, ar1, br1);                                              \
    __builtin_amdgcn_s_setprio(0);                                      \
    BARRIER;                                                            \
    /* P4 (m1,n0): reuse ar1,br0; stage PB B23 (tile T+2); vmcnt(4) */  \
    SBg(PB, 2, s2); SBg(PB, 3, s2);                                     \
    __builtin_amdgcn_s_setprio(1);                                      \
    MFMAQ(1, 0, ar1, br0);                                              \
    __builtin_amdgcn_s_setprio(0);                                      \
    VMCNT(4);                                                           \
    BARRIER;                                                            \
  }

  for (int T = 0; T < nk; T += 2) {
    TILEBODY(0, 32768, T);
    TILEBODY(32768, 0, T + 1);
  }
  VMCNT(0);

  // epilogue: wave rows {wm*64.., 128+wm*64..}, cols {wn*32.., 128+wn*32..}
#pragma unroll
  for (int ms = 0; ms < 2; ++ms)
#pragma unroll
    for (int fm = 0; fm < 4; ++fm) {
      const int row0 = bm * 256 + ms * 128 + wm * 64 + fm * 16 + ((lane >> 4) * 4);
#pragma unroll
      for (int ns = 0; ns < 2; ++ns)
#pragma unroll
        for (int fn = 0; fn < 2; ++fn) {
          const int col = bn * 256 + ns * 128 + wn * 32 + fn * 16 + lb15;
          const float bv = bias ? bias[col] : 0.0f;
#pragma unroll
          for (int r = 0; r < 4; ++r)
            C[(size_t)(row0 + r) * N + col] = f2b(acc[ms][fm][ns][fn][r] + bv);
        }
    }
#undef SAg
#undef SBg
#undef LDA
#undef LDB
#undef MFMAQ
#undef TILEBODY
}

// ---------- kernel 4: fused scatter/gather + gates ----------
__global__ __launch_bounds__(256) void fused_epi(
    const u16* __restrict__ XO, const u16* __restrict__ HO,
    const float* __restrict__ h0, const float* __restrict__ c0,
    const int* __restrict__ idd, const int* __restrict__ idr,
    const int* __restrict__ idl, float* __restrict__ outh,
    float* __restrict__ outc, int b0) {
  __shared__ int listD[512], listR[512], listL[512];
  __shared__ int cnt[3];
  const int j = blockIdx.x;
  const int lb = blockIdx.y;
  const int b = b0 + lb;
  const int tid = threadIdx.x;
  const int lane = tid & 63;
  const int wave = tid >> 6;

  if (wave < 3) {
    const int* ids = (wave == 0 ? idd : (wave == 1 ? idr : idl)) + (size_t)b * 512;
    int* lst = (wave == 0 ? listD : (wave == 1 ? listR : listL));
    int base = 0;
#pragma unroll
    for (int c2 = 0; c2 < 8; ++c2) {
      int l = c2 * 64 + lane;
      int id = ids[l];
      u64 m = __ballot(id == j);
      if (id == j) {
        int pos = __popcll(m & ((1ull << lane) - 1ull));
        lst[base + pos] = l;
      }
      base += __popcll(m);
    }
    if (lane == 0) cnt[wave] = base;
  }
  __syncthreads();

  const int nD = cnt[0], nR = cnt[1], nL = cnt[2];
  const size_t grow = (size_t)b * 512 + j;
  const int k = tid * 4;

  if (!((nD > 0) && (j != 0))) {
    f32x4 hv = *(const f32x4*)(h0 + grow * 1024 + k);
    f32x4 cv = *(const f32x4*)(c0 + grow * 1024 + k);
    *(f32x4*)(outh + grow * 1024 + k) = hv;
    *(f32x4*)(outc + grow * 1024 + k) = cv;
    return;
  }

  const size_t lrow = (size_t)lb * 512 + j;
  const u16* xo = XO + lrow * 4096;
  f32x4 ai = ldb4(xo + k);
  f32x4 ao = ldb4(xo + 1024 + k);
  f32x4 au = ldb4(xo + 2048 + k);
  f32x4 fx = ldb4(xo + 3072 + k);

  for (int t = 0; t < nR; ++t) {
    const u16* hr = HO + ((size_t)lb * 512 + listR[t]) * 8192;
    ai += ldb4(hr + k);
    ao += ldb4(hr + 1024 + k);
    au += ldb4(hr + 2048 + k);
  }
  for (int t = 0; t < nL; ++t) {
    const u16* hl = HO + ((size_t)lb * 512 + listL[t]) * 8192;
    ai += ldb4(hl + 3072 + k);
    ao += ldb4(hl + 4096 + k);
    au += ldb4(hl + 5120 + k);
  }
  f32x4 gi = sigm4(ai), go = sigm4(ao), gu = tanh4(au);
  f32x4 c = gi * gu;
  for (int t = 0; t < nD; ++t) {
    int child = listD[t];
    int rr = idr[(size_t)b * 512 + child];
    int ll = idl[(size_t)b * 512 + child];
    f32x4 fpre = fx + ldb4(HO + ((size_t)lb * 512 + rr) * 8192 + 6144 + k) +
                 ldb4(HO + ((size_t)lb * 512 + ll) * 8192 + 7168 + k);
    f32x4 fg = sigm4(fpre);
    f32x4 cc = *(const f32x4*)(c0 + ((size_t)b * 512 + child) * 1024 + k);
    c += fg * cc;
  }
  f32x4 h = go * tanh4(c);
  *(f32x4*)(outh + grow * 1024 + k) = h;
  *(f32x4*)(outc + grow * 1024 + k) = c;
}

// ---------- host ----------
extern "C" void kernel_launch(void* const* d_in, const int* in_sizes, int n_in,
                              void* d_out, int out_size, void* d_ws,
                              size_t ws_size, hipStream_t stream) {
  const float* x = (const float*)d_in[0];
  const float* h0 = (const float*)d_in[1];
  const float* c0 = (const float*)d_in[2];
  const float* W_ioux = (const float*)d_in[3];
  const float* b_ioux = (const float*)d_in[4];
  const float* W_iouh_r = (const float*)d_in[5];
  const float* W_iouh_l = (const float*)d_in[6];
  const float* W_fx = (const float*)d_in[7];
  const float* b_fx = (const float*)d_in[8];
  const float* W_fh0 = (const float*)d_in[9];
  const float* W_fh1 = (const float*)d_in[10];
  const float* W_fh2 = (const float*)d_in[11];
  const float* W_fh3 = (const float*)d_in[12];
  const int* idd = (const int*)d_in[13];
  const int* idr = (const int*)d_in[14];
  const int* idl = (const int*)d_in[15];

  const size_t M = 16384;  // B*L
  char* p = (char*)d_ws;
  u16* Xb = (u16*)p;   p += M * 1024 * 2;
  u16* Hb = (u16*)p;   p += M * 1024 * 2;
  u16* WxT = (u16*)p;  p += (size_t)4096 * 1024 * 2;
  u16* WhT = (u16*)p;  p += (size_t)8192 * 1024 * 2;
  float* bcat = (float*)p; p += (size_t)4096 * 4;
  const size_t base_sz = (size_t)(p - (char*)d_ws);
  const size_t per_cb = (size_t)512 * 4096 * 2 + (size_t)512 * 8192 * 2;
  int CB = 32;
  while (CB > 1 && base_sz + (size_t)CB * per_cb > ws_size) CB >>= 1;
  u16* XO = (u16*)p;   p += (size_t)CB * 512 * 4096 * 2;
  u16* HO = (u16*)p;

  float* outh = (float*)d_out;
  float* outc = outh + M * 1024;

  cvt2_kernel<<<2048, 256, 0, stream>>>((const f32x4*)x, (const f32x4*)h0,
                                        (u16x4*)Xb, (u16x4*)Hb,
                                        (int)(M * 1024 / 4));
  packw_kernel<<<6144, 256, 0, stream>>>(W_ioux, b_ioux, W_iouh_r, W_iouh_l,
                                         W_fx, b_fx, W_fh0, W_fh1, W_fh2, W_fh3,
                                         WxT, WhT, bcat);

  const int nc = 32 / CB;
  for (int c = 0; c < nc; ++c) {
    const int mrows = CB * 512;
    const u16* Ax = Xb + (size_t)c * CB * 512 * 1024;
    const u16* Ah = Hb + (size_t)c * CB * 512 * 1024;
    gemm_bt<<<(mrows / 256) * (4096 / 256), 512, 0, stream>>>(Ax, WxT, XO, bcat,
                                                              4096, 1024 / 64);
    gemm_bt<<<(mrows / 256) * (8192 / 256), 512, 0, stream>>>(Ah, WhT, HO,
                                                              nullptr, 8192,
                                                              1024 / 64);
    fused_epi<<<dim3(512, CB), 256, 0, stream>>>(XO, HO, h0, c0, idd, idr, idl,
                                                 outh, outc, c * CB);
  }
}